// Round 4
// baseline (721.317 us; speedup 1.0000x reference)
//
#include <hip/hip_runtime.h>
#include <stdint.h>

// ---------------- problem constants ----------------
#define B_   4
#define A_   25200
#define NC_  80
#define ROW_ 85          // 5 + NC
#define ATT_ 980         // 5 * 14 * 14
#define MAXDET_ 100
#define TOPK_ 1024
#define CAP_  2048       // candidate buffer per batch (fine 1024-bin hist -> n ~ 1024+60)
#define NBIN_ 1024
#define BINBASE_ 64000   // (0x3E800000 >> 14): key>>14 for score 0.25
#define OUTSTRIDE_ 25606 // 4 + 1 + 1 + 160*160
#define HW_ 160
#define HWHW_ 25600
#define CONF_ 0.25f
#define IOUT_ 0.45f

// ---------------- workspace layout (bytes) ----------------
#define WS_HIST 0         // 4 * 1024 u32 = 16384
#define WS_CNT  16384     // 4 u32
#define WS_CAND 16448     // 4 * 2048 u64 = 65536 -> [16448, 81984)
#define WS_DETA 81984     // 400 i32
// total ~84 KB

typedef unsigned long long u64;
typedef unsigned u32;

// ---------------- K0: clear hist + counters ----------------
__global__ void k_clear(char* w) {
    int i = blockIdx.x * 256 + threadIdx.x;
    if (i < B_ * NBIN_ + 4) ((u32*)w)[i] = 0u;   // hist (4096 words) + cnt (4 words)
}

// ---------------- K1: score histogram (1024 float-bit buckets) ----------------
__global__ void k_hist(const float* __restrict__ test, char* __restrict__ w) {
    int b = blockIdx.y;
    __shared__ u32 h[NBIN_];
    for (int i = threadIdx.x; i < NBIN_; i += 256) h[i] = 0u;
    __syncthreads();
    const int total = A_ * NC_;
    for (int e = blockIdx.x * 256 + threadIdx.x; e < total; e += 128 * 256) {
        u32 a = (u32)e / 80u;
        u32 c = (u32)e - a * 80u;
        const float* row = test + ((size_t)b * A_ + a) * ROW_;
        float s = row[5 + c] * row[4];
        if (s > CONF_) {
            u32 key = __float_as_uint(s);
            int wb = (int)(key >> 14) - BINBASE_;
            wb = wb < 0 ? 0 : (wb > NBIN_ - 1 ? NBIN_ - 1 : wb);
            atomicAdd(&h[wb], 1u);
        }
    }
    __syncthreads();
    u32* hist = (u32*)(w + WS_HIST);
    for (int i = threadIdx.x; i < NBIN_; i += 256)
        if (h[i]) atomicAdd(&hist[b * NBIN_ + i], h[i]);
}

// ---------------- K2: collect candidates >= threshold bucket ----------------
// threshold bin computed redundantly per block via two-level LDS suffix-scan.
__global__ void k_collect(const float* __restrict__ test, char* __restrict__ w) {
    int b = blockIdx.y;
    int tid = threadIdx.x;
    __shared__ u32 hb[NBIN_];
    __shared__ u32 cs[256];
    __shared__ int swtb;
    const u32* hist = (const u32*)(w + WS_HIST) + (size_t)b * NBIN_;
    for (int i = tid; i < NBIN_; i += 256) hb[i] = hist[i];
    if (tid == 0) swtb = 0;
    __syncthreads();
    // level-1: per-thread chunk of 4 bins
    u32 c0 = hb[4 * tid], c1 = hb[4 * tid + 1], c2 = hb[4 * tid + 2], c3 = hb[4 * tid + 3];
    cs[tid] = c0 + c1 + c2 + c3;
    __syncthreads();
    // Hillis-Steele suffix sums over 256 chunk sums
    for (int off = 1; off < 256; off <<= 1) {
        u32 v = cs[tid];
        if (tid + off < 256) v += cs[tid + off];
        __syncthreads();
        cs[tid] = v;
        __syncthreads();
    }
    {
        u32 tail = (tid < 255) ? cs[tid + 1] : 0u;  // suffix starting at bin 4*(tid+1)
        u32 s3 = tail + c3;
        u32 s2 = s3 + c2;
        u32 s1 = s2 + c1;
        u32 s0 = s1 + c0;
        // wtb = max bin i with suffix(i) >= TOPK  (exactly one boundary matches)
        if (s3 >= TOPK_ && tail < TOPK_) swtb = 4 * tid + 3;
        if (s2 >= TOPK_ && s3 < TOPK_)  swtb = 4 * tid + 2;
        if (s1 >= TOPK_ && s2 < TOPK_)  swtb = 4 * tid + 1;
        if (s0 >= TOPK_ && s1 < TOPK_)  swtb = 4 * tid + 0;
    }
    __syncthreads();
    int wtb = swtb;

    u32* cnt = (u32*)(w + WS_CNT);
    u64* cand = (u64*)(w + WS_CAND);
    const int total = A_ * NC_;
    for (int e = blockIdx.x * 256 + tid; e < total; e += 128 * 256) {
        u32 a = (u32)e / 80u;
        u32 c = (u32)e - a * 80u;
        const float* row = test + ((size_t)b * A_ + a) * ROW_;
        float sc = row[5 + c] * row[4];
        if (sc > CONF_) {
            u32 key = __float_as_uint(sc);
            int wb = (int)(key >> 14) - BINBASE_;
            wb = wb < 0 ? 0 : (wb > NBIN_ - 1 ? NBIN_ - 1 : wb);
            if (wb >= wtb) {
                u32 pos = atomicAdd(&cnt[b], 1u);
                if (pos < CAP_)
                    cand[(size_t)b * CAP_ + pos] = ((u64)key << 32) | (u64)(0xFFFFFFFFu - (u32)e);
            }
        }
    }
}

// exact-numpy IoU suppression test (no FMA contraction -> matches np bitwise)
__device__ __forceinline__ bool sup_pair(float4 a, float4 b, int ca, int cbb) {
#pragma clang fp contract(off)
    if (ca != cbb) return false;
    float areaA = fmaxf(a.z - a.x, 0.f) * fmaxf(a.w - a.y, 0.f);
    float areaB = fmaxf(b.z - b.x, 0.f) * fmaxf(b.w - b.y, 0.f);
    float ltx = fmaxf(a.x, b.x), lty = fmaxf(a.y, b.y);
    float rbx = fminf(a.z, b.z), rby = fminf(a.w, b.w);
    float iw = fmaxf(rbx - ltx, 0.f), ih = fmaxf(rby - lty, 0.f);
    float inter = iw * ih;
    float iou = inter / (((areaA + areaB) - inter) + 1e-9f);
    return iou > IOUT_;
}

__device__ __forceinline__ u64 maxu(u64 a, u64 b) { return a > b ? a : b; }
__device__ __forceinline__ u64 minu(u64 a, u64 b) { return a < b ? a : b; }
__device__ __forceinline__ u64 shflx(u64 v, int m) {
    int lo = __shfl_xor((int)(u32)v, m);
    int hi = __shfl_xor((int)(v >> 32), m);
    return ((u64)(u32)hi << 32) | (u32)lo;
}

// ---------------- K3: register-bitonic sort + in-LDS greedy NMS ----------------
// Thread (wave wv, lane l) owns elements x1 = wv*128+l and x2 = x1+64 of the
// 2048-wide sort window. Bitonic steps with j<=32 are pure __shfl_xor
// exchanges; j==64 is in-thread; only the 10 steps with j>=128 touch LDS
// (20 barriers total vs 66 for the all-LDS version).
__global__ __launch_bounds__(1024) void k_sortnms(const float* __restrict__ test,
                                                  char* __restrict__ w,
                                                  float* __restrict__ out) {
    int b = blockIdx.x;
    int tid = threadIdx.x;
    int lane = tid & 63, wv = tid >> 6;
    int x1 = wv * 128 + lane, x2 = x1 + 64;

    __shared__ u64 lds[CAP_];         // 16 KB (sort exchange buffer)
    __shared__ float4 cbs[TOPK_];     // 16 KB
    __shared__ float tvs[TOPK_];      // 4 KB
    __shared__ int tcs[TOPK_];        // 4 KB
    __shared__ int tas[TOPK_];        // 4 KB
    __shared__ u64 wmask[2][16];
    __shared__ int selA[MAXDET_];
    __shared__ int okA[MAXDET_];

    u32 cnt = ((const u32*)(w + WS_CNT))[b];
    int n = cnt < CAP_ ? (int)cnt : CAP_;
    const u64* cand = (const u64*)(w + WS_CAND) + (size_t)b * CAP_;
    u64 v1 = (x1 < n) ? cand[x1] : 0ull;
    u64 v2 = (x2 < n) ? cand[x2] : 0ull;

    // bitonic sort of 2048, descending (key desc, then smaller idx via ~idx low)
    for (int k = 2; k <= CAP_; k <<= 1) {
        // LDS steps: j >= 128 (cross-wave)
        for (int j = k >> 1; j >= 128; j >>= 1) {
            __syncthreads();               // prior readers done before overwrite
            lds[x1] = v1; lds[x2] = v2;
            __syncthreads();
            u64 u1 = lds[x1 ^ j], u2 = lds[x2 ^ j];
            bool q1 = ((x1 & j) == 0) == ((x1 & k) == 0);
            bool q2 = ((x2 & j) == 0) == ((x2 & k) == 0);
            v1 = q1 ? maxu(v1, u1) : minu(v1, u1);
            v2 = q2 ? maxu(v2, u2) : minu(v2, u2);
        }
        // j == 64: both elements in this thread (only occurs when k >= 128)
        if (k >= 128) {
            bool de = (x1 & k) == 0;      // == (x2 & k) since k != 64
            u64 a = de ? maxu(v1, v2) : minu(v1, v2);
            u64 c = de ? minu(v1, v2) : maxu(v1, v2);
            v1 = a; v2 = c;
        }
        // shuffle steps: j <= 32 (within-wave lane exchange)
        for (int j = (k >> 1) < 32 ? (k >> 1) : 32; j >= 1; j >>= 1) {
            u64 u1 = shflx(v1, j), u2 = shflx(v2, j);
            bool lo = (lane & j) == 0;
            bool q1 = lo == ((x1 & k) == 0);
            bool q2 = lo == ((x2 & k) == 0);
            v1 = q1 ? maxu(v1, u1) : minu(v1, u1);
            v2 = q2 ? maxu(v2, u2) : minu(v2, u2);
        }
    }

    int ntop = n < TOPK_ ? n : TOPK_;
    // decode ranks < 1024 straight from registers into LDS arrays
    {
        u64 vv[2] = { v1, v2 };
        int xx[2] = { x1, x2 };
#pragma unroll
        for (int r = 0; r < 2; ++r) {
            int x = xx[r];
            if (x < TOPK_) {
                if (x < ntop) {
                    u64 v = vv[r];
                    u32 key = (u32)(v >> 32);
                    u32 idx = 0xFFFFFFFFu - (u32)(v & 0xFFFFFFFFull);
                    u32 anchor = idx / 80u;
                    u32 cls = idx - anchor * 80u;
                    const float* tr = test + ((size_t)b * A_ + anchor) * ROW_;
                    float cx = tr[0], cy = tr[1], ww = tr[2], hh = tr[3];
                    float4 box;
                    box.x = cx - 0.5f * ww; box.y = cy - 0.5f * hh;
                    box.z = cx + 0.5f * ww; box.w = cy + 0.5f * hh;
                    tvs[x] = __uint_as_float(key);
                    tas[x] = (int)anchor; tcs[x] = (int)cls; cbs[x] = box;
                } else {
                    tvs[x] = 0.f; tas[x] = 0; tcs[x] = 0;
                    cbs[x] = make_float4(0.f, 0.f, 0.f, 0.f);
                }
            }
        }
    }
    __syncthreads();

    // greedy NMS: thread tid owns candidate rank tid. One barrier per round:
    // wave masks are double-buffered by round parity; every thread scans the
    // 16 words (broadcast LDS reads) to find j redundantly.
    bool valid = (tid < ntop);
    float4 myb = cbs[tid];
    int myc = tcs[tid];
    int par = 0;
    for (int k = 0; k < MAXDET_; ++k) {
        u64 bal = __ballot(valid);
        if (lane == 0) wmask[par][wv] = bal;
        __syncthreads();
        int j = -1;
#pragma unroll
        for (int q = 15; q >= 0; --q) {
            u64 m = wmask[par][q];
            if (m) j = (q << 6) + __ffsll(m) - 1;
        }
        if (j < 0) {                      // uniform: all threads agree
            if (tid == 0)
                for (int kk = k; kk < MAXDET_; ++kk) { selA[kk] = 0; okA[kk] = 0; }
            break;
        }
        if (tid == 0) { selA[k] = j; okA[k] = 1; }
        if (valid && (tid == j || sup_pair(cbs[j], myb, tcs[j], myc))) valid = false;
        par ^= 1;
    }
    __syncthreads();

    // write detection headers + selected anchors
    int* deta = (int*)(w + WS_DETA);
    for (int k = tid; k < MAXDET_; k += 1024) {
        int ok = okA[k], s = selA[k];
        float b0 = 0, b1 = 0, b2 = 0, b3 = 0, sc = 0; int cls_ = 0, anc = 0;
        if (ok) {
            float4 bb = cbs[s];
            b0 = bb.x; b1 = bb.y; b2 = bb.z; b3 = bb.w;
            sc = tvs[s]; cls_ = tcs[s]; anc = tas[s];
        }
        size_t o = ((size_t)(b * MAXDET_ + k)) * OUTSTRIDE_;
        out[o + 0] = b0; out[o + 1] = b1; out[o + 2] = b2; out[o + 3] = b3;
        out[o + 4] = sc; out[o + 5] = (float)cls_;
        deta[b * MAXDET_ + k] = anc;
    }
}

// ---------------- K4: ROI-align + coeff-resize + softmax + sigmoid masks ----
__global__ void k_mask(const float* __restrict__ test, const float* __restrict__ attn,
                       const float* __restrict__ bases, const float* __restrict__ sem,
                       const char* __restrict__ w, float* __restrict__ out) {
    int roi = blockIdx.x;          // 0..399
    int b = roi / MAXDET_;
    int anchor = ((const int*)(w + WS_DETA))[roi];
    const float* t = test + ((size_t)b * A_ + anchor) * ROW_;
    float cx = t[0], cy = t[1], ww = t[2], hh = t[3];
    float bx1 = cx - 0.5f * ww, by1 = cy - 0.5f * hh;
    float bx2 = cx + 0.5f * ww, by2 = cy + 0.5f * hh;
    float rx1 = bx1 * 0.25f - 0.5f, ry1 = by1 * 0.25f - 0.5f;
    float rx2 = bx2 * 0.25f - 0.5f, ry2 = by2 * 0.25f - 0.5f;
    float xstep = (rx2 - rx1) / 160.f, ystep = (ry2 - ry1) / 160.f;

    __shared__ float att[5 * 196];
    __shared__ float sxw[HW_], syw[HW_], rzw[HW_];
    __shared__ int sxlo[HW_], sxhi[HW_], sylo[HW_], syhi[HW_];
    __shared__ int sxv[HW_], syv[HW_], rzlo[HW_];

    const float* arow = attn + ((size_t)b * A_ + anchor) * ATT_;
    for (int i = threadIdx.x; i < ATT_; i += 256) att[i] = arow[i];
    if (threadIdx.x < HW_) {
        int i = threadIdx.x;
        float coord = rx1 + (i + 0.5f) * xstep;
        sxv[i] = (coord > -1.0f) && (coord < 160.0f);
        float c = fminf(fmaxf(coord, 0.f), 159.f);
        float lo = floorf(c);
        sxlo[i] = (int)lo; sxhi[i] = min((int)lo + 1, 159); sxw[i] = c - lo;
        coord = ry1 + (i + 0.5f) * ystep;
        syv[i] = (coord > -1.0f) && (coord < 160.0f);
        c = fminf(fmaxf(coord, 0.f), 159.f);
        lo = floorf(c);
        sylo[i] = (int)lo; syhi[i] = min((int)lo + 1, 159); syw[i] = c - lo;
        // 14 -> 160 half-pixel linear resize (clamped == jax normalized triangle)
        float f = (i + 0.5f) * (14.f / 160.f) - 0.5f;
        float rc = fminf(fmaxf(f, 0.f), 13.f);
        float rlo = floorf(rc);
        rzlo[i] = (int)rlo; rzw[i] = rc - rlo;
    }
    __syncthreads();

    const float* bp[5];
    bp[0] = bases + ((size_t)b * 4 + 0) * HWHW_;
    bp[1] = bases + ((size_t)b * 4 + 1) * HWHW_;
    bp[2] = bases + ((size_t)b * 4 + 2) * HWHW_;
    bp[3] = bases + ((size_t)b * 4 + 3) * HWHW_;
    bp[4] = sem + (size_t)b * HWHW_;

    size_t obase = (size_t)roi * OUTSTRIDE_ + 6;
    int pstart = blockIdx.y * (HWHW_ / 8);
    int pend = pstart + (HWHW_ / 8);
    for (int p = pstart + (int)threadIdx.x; p < pend; p += 256) {
        int y = p / HW_, x = p - y * HW_;
        int ylo = sylo[y], yhi = syhi[y]; float wy = syw[y];
        int xlo = sxlo[x], xhi = sxhi[x]; float wx = sxw[x];
        bool v = sxv[x] && syv[y];
        float w00 = (1.f - wy) * (1.f - wx), w01 = (1.f - wy) * wx;
        float w10 = wy * (1.f - wx), w11 = wy * wx;
        int i00 = ylo * HW_ + xlo, i01 = ylo * HW_ + xhi;
        int i10 = yhi * HW_ + xlo, i11 = yhi * HW_ + xhi;
        float pooled[5];
#pragma unroll
        for (int c5 = 0; c5 < 5; ++c5) {
            float g = bp[c5][i00] * w00 + bp[c5][i01] * w01 + bp[c5][i10] * w10 + bp[c5][i11] * w11;
            pooled[c5] = v ? g : 0.f;
        }
        int cylo = rzlo[y]; float cwy = rzw[y]; int cyhi = min(cylo + 1, 13);
        int cxlo = rzlo[x]; float cwx = rzw[x]; int cxhi = min(cxlo + 1, 13);
        float c00 = (1.f - cwy) * (1.f - cwx), c01 = (1.f - cwy) * cwx;
        float c10 = cwy * (1.f - cwx), c11 = cwy * cwx;
        int j00 = cylo * 14 + cxlo, j01 = cylo * 14 + cxhi;
        int j10 = cyhi * 14 + cxlo, j11 = cyhi * 14 + cxhi;
        float cf[5]; float m = -1e30f;
#pragma unroll
        for (int c5 = 0; c5 < 5; ++c5) {
            const float* ap = att + c5 * 196;
            float g = ap[j00] * c00 + ap[j01] * c01 + ap[j10] * c10 + ap[j11] * c11;
            cf[c5] = g; m = fmaxf(m, g);
        }
        float se = 0.f, dot = 0.f;
#pragma unroll
        for (int c5 = 0; c5 < 5; ++c5) {
            float e = __expf(cf[c5] - m);
            se += e; dot += pooled[c5] * e;
        }
        dot /= se;
        out[obase + p] = 1.f / (1.f + __expf(-dot));
    }
}

extern "C" void kernel_launch(void* const* d_in, const int* in_sizes, int n_in,
                              void* d_out, int out_size, void* d_ws, size_t ws_size,
                              hipStream_t stream) {
    const float* test = (const float*)d_in[0];
    const float* attn = (const float*)d_in[1];
    const float* bases = (const float*)d_in[2];
    const float* sem = (const float*)d_in[3];
    float* out = (float*)d_out;
    char* w = (char*)d_ws;   // needs ~84 KB

    k_clear<<<17, 256, 0, stream>>>(w);
    k_hist<<<dim3(128, B_), 256, 0, stream>>>(test, w);
    k_collect<<<dim3(128, B_), 256, 0, stream>>>(test, w);
    k_sortnms<<<B_, 1024, 0, stream>>>(test, w, out);
    k_mask<<<dim3(B_ * MAXDET_, 8), 256, 0, stream>>>(test, attn, bases, sem, w, out);
}